// Round 12
// baseline (15334.711 us; speedup 1.0000x reference)
//
#include <hip/hip_runtime.h>
#include <math.h>

#define A_PL 22
#define F_IN_ 16
#define T_LEN 256
#define NBLK_SEQ 64

__device__ __forceinline__ float sigmoidf_(float x) { return 1.f / (1.f + __expf(-x)); }

// Cross-XCD-safe handoff (per-op agent-scope atomics; validated R9 absmax 0.0).
__device__ __forceinline__ void gstore(float* p, float v) {
  __hip_atomic_store(p, v, __ATOMIC_RELAXED, __HIP_MEMORY_SCOPE_AGENT);
}
__device__ __forceinline__ float gload(const float* p) {
  return __hip_atomic_load(p, __ATOMIC_RELAXED, __HIP_MEMORY_SCOPE_AGENT);
}

// Fast grid barrier: monotonic arrival counter in L2. Release on arrival
// (ACQ_REL RMW orders this block's prior agent stores), ACQUIRE poll with
// s_sleep backoff. ~2-3us for 64 blocks vs ~30us for cg grid.sync (R9).
// Counter zeroed by the launch-start memset -> graph-replay safe.
__device__ __forceinline__ void gbar(unsigned int* cnt, unsigned int tgt) {
  __syncthreads();
  if (threadIdx.x == 0) {
    __hip_atomic_fetch_add(cnt, 1u, __ATOMIC_ACQ_REL, __HIP_MEMORY_SCOPE_AGENT);
    while (__hip_atomic_load(cnt, __ATOMIC_ACQUIRE, __HIP_MEMORY_SCOPE_AGENT) < tgt) {
      __builtin_amdgcn_s_sleep(1);
    }
  }
  __syncthreads();
}

// seq_lengths: int64 or int32. True values in [128,256], never 0 =>
// little-endian int64 has lens32[1]==0.
__device__ __forceinline__ int read_len(const int* __restrict__ lens, int b) {
  return (lens[1] == 0) ? lens[2 * b] : lens[b];
}

// ---------------------------------------------------------------------------
// Kernel 1: NAIVE fused GAT (proven correct in R8 — untouched).
// ---------------------------------------------------------------------------
__global__ __launch_bounds__(256) void gat_naive(
    const float* __restrict__ feat, const int* __restrict__ lens,
    const float* __restrict__ W1, const float* __restrict__ as1,
    const float* __restrict__ ad1, const float* __restrict__ b1,
    const float* __restrict__ W2, const float* __restrict__ as2,
    const float* __restrict__ ad2, const float* __restrict__ b2,
    float* __restrict__ pooled)
{
  const int n = blockIdx.x;
  const int tid = threadIdx.x;
  const int bb = n >> 8;          // batch
  const int tt = n & 255;         // time
  if (tt >= read_len(lens, bb)) { // masked frame: pooled = 0
    if (tid < 128) pooled[(size_t)n * 128 + tid] = 0.f;
    return;
  }

  __shared__ float xs[352];       // x [22][16]
  __shared__ float hbuf[2816];    // per-head h [22][128]; later h2 [22][128]
  __shared__ float x2s[11264];    // GAT1 output [22][512] (relu'd)
  __shared__ float asrc[22], adst[22], alpha[484];

  for (int i = tid; i < 352; i += 256) xs[i] = feat[(size_t)n * 352 + i];
  __syncthreads();

  for (int hd = 0; hd < 4; hd++) {
    for (int i = tid; i < 2816; i += 256) {
      int a = i >> 7, c = i & 127;
      float acc = 0.f;
      for (int f = 0; f < 16; f++) acc += xs[a * 16 + f] * W1[f * 512 + hd * 128 + c];
      hbuf[i] = acc;
    }
    __syncthreads();
    if (tid < 44) {
      int a = tid >> 1;
      const float* av = (tid & 1) ? ad1 : as1;
      float s = 0.f;
      for (int c = 0; c < 128; c++) s += hbuf[a * 128 + c] * av[hd * 128 + c];
      ((tid & 1) ? adst : asrc)[a] = s;
    }
    __syncthreads();
    if (tid < 22) {
      float ev[22], m = -1e30f;
      for (int j = 0; j < 22; j++) {
        float e = adst[tid] + asrc[j];
        e = (e > 0.f) ? e : 0.2f * e;
        ev[j] = e; if (e > m) m = e;
      }
      float s = 0.f;
      for (int j = 0; j < 22; j++) { ev[j] = __expf(ev[j] - m); s += ev[j]; }
      float inv = 1.f / s;
      for (int j = 0; j < 22; j++) alpha[tid * 22 + j] = ev[j] * inv;
    }
    __syncthreads();
    for (int i = tid; i < 2816; i += 256) {
      int a = i >> 7, c = i & 127;
      float acc = 0.f;
      for (int j = 0; j < 22; j++) acc += alpha[a * 22 + j] * hbuf[j * 128 + c];
      x2s[a * 512 + hd * 128 + c] = fmaxf(acc + b1[hd * 128 + c], 0.f);
    }
    __syncthreads();
  }

  for (int i = tid; i < 2816; i += 256) {
    int a = i >> 7, c = i & 127;
    float acc = 0.f;
    for (int k = 0; k < 512; k++) acc += x2s[a * 512 + k] * W2[(size_t)k * 128 + c];
    hbuf[i] = acc;
  }
  __syncthreads();
  if (tid < 44) {
    int a = tid >> 1;
    const float* av = (tid & 1) ? ad2 : as2;
    float s = 0.f;
    for (int c = 0; c < 128; c++) s += hbuf[a * 128 + c] * av[c];
    ((tid & 1) ? adst : asrc)[a] = s;
  }
  __syncthreads();
  if (tid < 22) {
    float ev[22], m = -1e30f;
    for (int j = 0; j < 22; j++) {
      float e = adst[tid] + asrc[j];
      e = (e > 0.f) ? e : 0.2f * e;
      ev[j] = e; if (e > m) m = e;
    }
    float s = 0.f;
    for (int j = 0; j < 22; j++) { ev[j] = __expf(ev[j] - m); s += ev[j]; }
    float inv = 1.f / s;
    for (int j = 0; j < 22; j++) alpha[tid * 22 + j] = ev[j] * inv;
  }
  __syncthreads();
  if (tid < 128) {
    float s = 0.f;
    for (int a = 0; a < 22; a++) {
      float v = b2[tid];
      for (int j = 0; j < 22; j++) v += alpha[a * 22 + j] * hbuf[j * 128 + tid];
      s += fmaxf(v, 0.f);
    }
    pooled[(size_t)n * 128 + tid] = s * (1.f / 22.f);
  }
}

// ---------------------------------------------------------------------------
// Kernel 2: split-j LSTM = R9's kernel VERBATIM except grid.sync() -> gbar()
// (R9 measured: compute ~2us/phase, grid.sync ~30us/phase -> 16.3ms best).
// 64 blocks; block owns 4 j-cells for all 32 batches; weights L1/L2-hot
// (56KB/block/step); h exchanged via ws; thread-pair split-K + __shfl_xor.
// Cooperative launch retained ONLY for the co-residency guarantee.
// ---------------------------------------------------------------------------
__global__ __launch_bounds__(256) void lstm_seq(
    const float* __restrict__ pooled,
    const float* __restrict__ Wih0, const float* __restrict__ bih0,
    const float* __restrict__ bhh0, const float* __restrict__ Whh0,
    const float* __restrict__ Wih1, const float* __restrict__ Whh1,
    const float* __restrict__ bih1, const float* __restrict__ bhh1,
    const int* __restrict__ lens,
    const float* __restrict__ clfw, const float* __restrict__ clfb,
    float* __restrict__ ws, float* __restrict__ out)
{
  __shared__ float shx[8192];   // 32 KB
  __shared__ float shh[8192];   // 32 KB

  unsigned int* cnt = (unsigned int*)ws;   // ws[0..63]: barrier line
  float* h0buf = ws + 64;              // [2][32][256]
  float* c0    = h0buf + 16384;        // [32][256]
  float* h1buf = c0 + 8192;            // [2][32][256]
  float* c1    = h1buf + 16384;        // [32][256]

  const int tid  = threadIdx.x;
  const int cell = tid >> 1;
  const int half = tid & 1;
  const int b    = cell & 31;
  const int jj   = cell >> 5;
  const int j    = blockIdx.x * 4 + jj;
  const int len_b = read_len(lens, b);

  const float bA0 = bih0[j]       + bhh0[j];
  const float bA1 = bih0[256 + j] + bhh0[256 + j];
  const float bA2 = bih0[512 + j] + bhh0[512 + j];
  const float bA3 = bih0[768 + j] + bhh0[768 + j];
  const float bB0 = bih1[j]       + bhh1[j];
  const float bB1 = bih1[256 + j] + bhh1[256 + j];
  const float bB2 = bih1[512 + j] + bhh1[512 + j];
  const float bB3 = bih1[768 + j] + bhh1[768 + j];

  const float* wA0 = Whh0 + (size_t)j * 256;
  const float* wA1 = Whh0 + (size_t)(256 + j) * 256;
  const float* wA2 = Whh0 + (size_t)(512 + j) * 256;
  const float* wA3 = Whh0 + (size_t)(768 + j) * 256;

  const float* wI0 = Wih0 + (size_t)j * 128         + half * 64;
  const float* wI1 = Wih0 + (size_t)(256 + j) * 128 + half * 64;
  const float* wI2 = Wih0 + (size_t)(512 + j) * 128 + half * 64;
  const float* wI3 = Wih0 + (size_t)(768 + j) * 128 + half * 64;

  unsigned int tgt = 0;

  for (int t = 0; t < T_LEN; t++) {
    const int cur = t & 1, prv = cur ^ 1;

    // ================= phase A: layer-0 step =================
    {
      const float* src = h0buf + prv * 8192;
      for (int i = tid; i < 8192; i += 256) {
        int bq = i >> 8, kq = i & 255;
        shx[kq * 32 + ((bq + kq) & 31)] = gload(src + i);
      }
    }
    __syncthreads();

    float a0 = 0.f, a1 = 0.f, a2 = 0.f, a3 = 0.f;
    {
      const int kbase = half * 128;
      for (int k4 = 0; k4 < 32; k4++) {
        int k = kbase + k4 * 4;
        float4 w0 = *(const float4*)(wA0 + k);
        float4 w1 = *(const float4*)(wA1 + k);
        float4 w2 = *(const float4*)(wA2 + k);
        float4 w3 = *(const float4*)(wA3 + k);
        #pragma unroll
        for (int u = 0; u < 4; u++) {
          int ku = k + u;
          float hv = shx[ku * 32 + ((b + ku) & 31)];
          a0 += hv * ((const float*)&w0)[u];
          a1 += hv * ((const float*)&w1)[u];
          a2 += hv * ((const float*)&w2)[u];
          a3 += hv * ((const float*)&w3)[u];
        }
      }
      const float* pp = pooled + ((size_t)(b * 256 + t)) * 128 + half * 64;
      for (int k4 = 0; k4 < 16; k4++) {
        float4 xv = *(const float4*)(pp + k4 * 4);
        float4 w0 = *(const float4*)(wI0 + k4 * 4);
        float4 w1 = *(const float4*)(wI1 + k4 * 4);
        float4 w2 = *(const float4*)(wI2 + k4 * 4);
        float4 w3 = *(const float4*)(wI3 + k4 * 4);
        a0 += xv.x * w0.x + xv.y * w0.y + xv.z * w0.z + xv.w * w0.w;
        a1 += xv.x * w1.x + xv.y * w1.y + xv.z * w1.z + xv.w * w1.w;
        a2 += xv.x * w2.x + xv.y * w2.y + xv.z * w2.z + xv.w * w2.w;
        a3 += xv.x * w3.x + xv.y * w3.y + xv.z * w3.z + xv.w * w3.w;
      }
    }
    a0 += __shfl_xor(a0, 1); a1 += __shfl_xor(a1, 1);
    a2 += __shfl_xor(a2, 1); a3 += __shfl_xor(a3, 1);

    {
      float iv = sigmoidf_(a0 + bA0);
      float fv = sigmoidf_(a1 + bA1);
      float gv = tanhf(a2 + bA2);
      float ov = sigmoidf_(a3 + bA3);
      float cold = c0[b * 256 + j];
      float cnew = fv * cold + iv * gv;
      float hnew = ov * tanhf(cnew);
      bool valid = t < len_b;
      float hprev = shx[j * 32 + ((b + j) & 31)];
      float hout = valid ? hnew : hprev;
      float cout = valid ? cnew : cold;
      if (half == 0) {
        c0[b * 256 + j] = cout;
        gstore(h0buf + cur * 8192 + b * 256 + j, hout);
      }
    }
    tgt += NBLK_SEQ;
    gbar(cnt, tgt);

    // ================= phase B: layer-1 step =================
    {
      const float* srcx = h0buf + cur * 8192;   // layer-0 output at t
      const float* srch = h1buf + prv * 8192;
      for (int i = tid; i < 8192; i += 256) {
        int bq = i >> 8, kq = i & 255;
        int a = kq * 32 + ((bq + kq) & 31);
        shx[a] = gload(srcx + i);
        shh[a] = gload(srch + i);
      }
    }
    __syncthreads();

    float s0 = 0.f, s1 = 0.f, s2 = 0.f, s3 = 0.f;
    {
      const float* Wb  = half ? Whh1 : Wih1;
      const float* hbf = half ? shh : shx;
      const float* r0 = Wb + (size_t)j * 256;
      const float* r1 = Wb + (size_t)(256 + j) * 256;
      const float* r2 = Wb + (size_t)(512 + j) * 256;
      const float* r3 = Wb + (size_t)(768 + j) * 256;
      for (int k4 = 0; k4 < 64; k4++) {
        int k = k4 * 4;
        float4 w0 = *(const float4*)(r0 + k);
        float4 w1 = *(const float4*)(r1 + k);
        float4 w2 = *(const float4*)(r2 + k);
        float4 w3 = *(const float4*)(r3 + k);
        #pragma unroll
        for (int u = 0; u < 4; u++) {
          int ku = k + u;
          float hv = hbf[ku * 32 + ((b + ku) & 31)];
          s0 += hv * ((const float*)&w0)[u];
          s1 += hv * ((const float*)&w1)[u];
          s2 += hv * ((const float*)&w2)[u];
          s3 += hv * ((const float*)&w3)[u];
        }
      }
    }
    s0 += __shfl_xor(s0, 1); s1 += __shfl_xor(s1, 1);
    s2 += __shfl_xor(s2, 1); s3 += __shfl_xor(s3, 1);

    {
      float iv = sigmoidf_(s0 + bB0);
      float fv = sigmoidf_(s1 + bB1);
      float gv = tanhf(s2 + bB2);
      float ov = sigmoidf_(s3 + bB3);
      float cold = c1[b * 256 + j];
      float cnew = fv * cold + iv * gv;
      float hnew = ov * tanhf(cnew);
      bool valid = t < len_b;
      float hprev = shh[j * 32 + ((b + j) & 31)];
      float hout = valid ? hnew : hprev;
      float cout = valid ? cnew : cold;
      if (half == 0) {
        c1[b * 256 + j] = cout;
        gstore(h1buf + cur * 8192 + b * 256 + j, hout);
      }
    }
    tgt += NBLK_SEQ;
    gbar(cnt, tgt);
  }

  // classifier: logits[b] = h1_last[b] . clf_w + clf_b (t=255 -> buf 1)
  if (blockIdx.x == 0 && tid < 32) {
    float s = clfb[0];
    const float* hl = h1buf + 8192 + tid * 256;
    for (int k = 0; k < 256; k++) s += gload(hl + k) * clfw[k];
    out[tid] = s;
  }
}

// ---------------------------------------------------------------------------
extern "C" void kernel_launch(void* const* d_in, const int* in_sizes, int n_in,
                              void* d_out, int out_size, void* d_ws, size_t ws_size,
                              hipStream_t stream) {
  (void)in_sizes; (void)n_in; (void)out_size; (void)ws_size;
  const float* feat = (const float*)d_in[0];
  const int*   lens = (const int*)d_in[1];
  const float* W1   = (const float*)d_in[2];
  const float* as1  = (const float*)d_in[3];
  const float* ad1  = (const float*)d_in[4];
  const float* b1   = (const float*)d_in[5];
  const float* W2   = (const float*)d_in[6];
  const float* as2  = (const float*)d_in[7];
  const float* ad2  = (const float*)d_in[8];
  const float* b2   = (const float*)d_in[9];
  const float* Wih0 = (const float*)d_in[10];
  const float* Whh0 = (const float*)d_in[11];
  const float* bih0 = (const float*)d_in[12];
  const float* bhh0 = (const float*)d_in[13];
  const float* Wih1 = (const float*)d_in[14];
  const float* Whh1 = (const float*)d_in[15];
  const float* bih1 = (const float*)d_in[16];
  const float* bhh1 = (const float*)d_in[17];
  const float* clfw = (const float*)d_in[18];
  const float* clfb = (const float*)d_in[19];

  float* ws     = (float*)d_ws;
  float* pooled = ws + 65536;   // [8192][128] -> total ws use 4.25 MB
  float* outp   = (float*)d_out;

  // zero barrier counter + LSTM state (h0/c0/h1/c1 double buffers)
  hipMemsetAsync(d_ws, 0, 65536 * sizeof(float), stream);

  gat_naive<<<8192, 256, 0, stream>>>(feat, lens, W1, as1, ad1, b1,
                                      W2, as2, ad2, b2, pooled);

  void* args[] = {
    (void*)&pooled, (void*)&Wih0, (void*)&bih0, (void*)&bhh0, (void*)&Whh0,
    (void*)&Wih1, (void*)&Whh1, (void*)&bih1, (void*)&bhh1,
    (void*)&lens, (void*)&clfw, (void*)&clfb, (void*)&ws, (void*)&outp
  };
  hipLaunchCooperativeKernel((const void*)lstm_seq, dim3(NBLK_SEQ), dim3(256),
                             args, 0, stream);
}

// Round 13
// 10132.193 us; speedup vs baseline: 1.5135x; 1.5135x over previous
//
#include <hip/hip_runtime.h>
#include <math.h>

#define A_PL 22
#define F_IN_ 16
#define T_LEN 256
#define NBLK_SEQ 64

__device__ __forceinline__ float sigmoidf_(float x) { return 1.f / (1.f + __expf(-x)); }

// Cross-XCD-safe handoff (per-op agent-scope atomics; validated R9/R12 absmax 0.0).
__device__ __forceinline__ void gstore(float* p, float v) {
  __hip_atomic_store(p, v, __ATOMIC_RELAXED, __HIP_MEMORY_SCOPE_AGENT);
}
__device__ __forceinline__ float gload(const float* p) {
  return __hip_atomic_load(p, __ATOMIC_RELAXED, __HIP_MEMORY_SCOPE_AGENT);
}

// Monotonic-counter grid barrier (R12-validated). s_sleep(4) backoff cuts
// poll pressure on the line while arrivals serialize.
__device__ __forceinline__ void gbar(unsigned int* cnt, unsigned int tgt) {
  __syncthreads();
  if (threadIdx.x == 0) {
    __hip_atomic_fetch_add(cnt, 1u, __ATOMIC_ACQ_REL, __HIP_MEMORY_SCOPE_AGENT);
    while (__hip_atomic_load(cnt, __ATOMIC_ACQUIRE, __HIP_MEMORY_SCOPE_AGENT) < tgt) {
      __builtin_amdgcn_s_sleep(4);
    }
  }
  __syncthreads();
}

// seq_lengths: int64 or int32. True values in [128,256], never 0 =>
// little-endian int64 has lens32[1]==0.
__device__ __forceinline__ int read_len(const int* __restrict__ lens, int b) {
  return (lens[1] == 0) ? lens[2 * b] : lens[b];
}

// ---------------------------------------------------------------------------
// Kernel 1: NAIVE fused GAT (proven correct in R8 — untouched).
// ---------------------------------------------------------------------------
__global__ __launch_bounds__(256) void gat_naive(
    const float* __restrict__ feat, const int* __restrict__ lens,
    const float* __restrict__ W1, const float* __restrict__ as1,
    const float* __restrict__ ad1, const float* __restrict__ b1,
    const float* __restrict__ W2, const float* __restrict__ as2,
    const float* __restrict__ ad2, const float* __restrict__ b2,
    float* __restrict__ pooled)
{
  const int n = blockIdx.x;
  const int tid = threadIdx.x;
  const int bb = n >> 8;          // batch
  const int tt = n & 255;         // time
  if (tt >= read_len(lens, bb)) { // masked frame: pooled = 0
    if (tid < 128) pooled[(size_t)n * 128 + tid] = 0.f;
    return;
  }

  __shared__ float xs[352];       // x [22][16]
  __shared__ float hbuf[2816];    // per-head h [22][128]; later h2 [22][128]
  __shared__ float x2s[11264];    // GAT1 output [22][512] (relu'd)
  __shared__ float asrc[22], adst[22], alpha[484];

  for (int i = tid; i < 352; i += 256) xs[i] = feat[(size_t)n * 352 + i];
  __syncthreads();

  for (int hd = 0; hd < 4; hd++) {
    for (int i = tid; i < 2816; i += 256) {
      int a = i >> 7, c = i & 127;
      float acc = 0.f;
      for (int f = 0; f < 16; f++) acc += xs[a * 16 + f] * W1[f * 512 + hd * 128 + c];
      hbuf[i] = acc;
    }
    __syncthreads();
    if (tid < 44) {
      int a = tid >> 1;
      const float* av = (tid & 1) ? ad1 : as1;
      float s = 0.f;
      for (int c = 0; c < 128; c++) s += hbuf[a * 128 + c] * av[hd * 128 + c];
      ((tid & 1) ? adst : asrc)[a] = s;
    }
    __syncthreads();
    if (tid < 22) {
      float ev[22], m = -1e30f;
      for (int j = 0; j < 22; j++) {
        float e = adst[tid] + asrc[j];
        e = (e > 0.f) ? e : 0.2f * e;
        ev[j] = e; if (e > m) m = e;
      }
      float s = 0.f;
      for (int j = 0; j < 22; j++) { ev[j] = __expf(ev[j] - m); s += ev[j]; }
      float inv = 1.f / s;
      for (int j = 0; j < 22; j++) alpha[tid * 22 + j] = ev[j] * inv;
    }
    __syncthreads();
    for (int i = tid; i < 2816; i += 256) {
      int a = i >> 7, c = i & 127;
      float acc = 0.f;
      for (int j = 0; j < 22; j++) acc += alpha[a * 22 + j] * hbuf[j * 128 + c];
      x2s[a * 512 + hd * 128 + c] = fmaxf(acc + b1[hd * 128 + c], 0.f);
    }
    __syncthreads();
  }

  for (int i = tid; i < 2816; i += 256) {
    int a = i >> 7, c = i & 127;
    float acc = 0.f;
    for (int k = 0; k < 512; k++) acc += x2s[a * 512 + k] * W2[(size_t)k * 128 + c];
    hbuf[i] = acc;
  }
  __syncthreads();
  if (tid < 44) {
    int a = tid >> 1;
    const float* av = (tid & 1) ? ad2 : as2;
    float s = 0.f;
    for (int c = 0; c < 128; c++) s += hbuf[a * 128 + c] * av[c];
    ((tid & 1) ? adst : asrc)[a] = s;
  }
  __syncthreads();
  if (tid < 22) {
    float ev[22], m = -1e30f;
    for (int j = 0; j < 22; j++) {
      float e = adst[tid] + asrc[j];
      e = (e > 0.f) ? e : 0.2f * e;
      ev[j] = e; if (e > m) m = e;
    }
    float s = 0.f;
    for (int j = 0; j < 22; j++) { ev[j] = __expf(ev[j] - m); s += ev[j]; }
    float inv = 1.f / s;
    for (int j = 0; j < 22; j++) alpha[tid * 22 + j] = ev[j] * inv;
  }
  __syncthreads();
  if (tid < 128) {
    float s = 0.f;
    for (int a = 0; a < 22; a++) {
      float v = b2[tid];
      for (int j = 0; j < 22; j++) v += alpha[a * 22 + j] * hbuf[j * 128 + tid];
      s += fmaxf(v, 0.f);
    }
    pooled[(size_t)n * 128 + tid] = s * (1.f / 22.f);
  }
}

// ---------------------------------------------------------------------------
// Kernel 2: software-pipelined split LSTM. 64 blocks = 8 j-groups x 8
// batch-groups (32 j x 4 batches per block). Phase p computes layer-0 step p
// AND layer-1 step p-1 (both consume data published at barrier p-1) ->
// ONE barrier per step (257 total, vs 512 in R12). Agent-scope staging is
// 8KB/block/phase (vs 96KB in R12). c-state in registers (block-local).
// Thread = (jl, bl, half): pair split-K + 1 __shfl_xor. LDS h rows padded
// to 264 floats -> <=2-way bank conflicts (free, m136).
// ---------------------------------------------------------------------------
__global__ __launch_bounds__(256) void lstm_pipe(
    const float* __restrict__ pooled,
    const float* __restrict__ Wih0, const float* __restrict__ bih0,
    const float* __restrict__ bhh0, const float* __restrict__ Whh0,
    const float* __restrict__ Wih1, const float* __restrict__ Whh1,
    const float* __restrict__ bih1, const float* __restrict__ bhh1,
    const int* __restrict__ lens,
    const float* __restrict__ clfw, const float* __restrict__ clfb,
    float* __restrict__ ws, float* __restrict__ out)
{
  __shared__ float h0p[4 * 264];   // h0[p-1] for our 4 batches (padded)
  __shared__ float h1p[4 * 264];   // h1[p-2]

  unsigned int* cnt = (unsigned int*)ws;   // ws[0..63]: barrier line
  float* h0buf = ws + 64;              // [2][32][256]
  float* h1buf = h0buf + 16384;        // [2][32][256]

  const int tid  = threadIdx.x;
  const int half = tid & 1;
  const int cell = tid >> 1;       // 0..127
  const int bl   = cell & 3;       // local batch 0..3
  const int jl   = cell >> 2;      // local j 0..31
  const int jg   = blockIdx.x & 7;
  const int bg   = blockIdx.x >> 3;
  const int j    = jg * 32 + jl;
  const int b    = bg * 4 + bl;
  const int len_b = read_len(lens, b);

  const float bA0 = bih0[j]       + bhh0[j];
  const float bA1 = bih0[256 + j] + bhh0[256 + j];
  const float bA2 = bih0[512 + j] + bhh0[512 + j];
  const float bA3 = bih0[768 + j] + bhh0[768 + j];
  const float bB0 = bih1[j]       + bhh1[j];
  const float bB1 = bih1[256 + j] + bhh1[256 + j];
  const float bB2 = bih1[512 + j] + bhh1[512 + j];
  const float bB3 = bih1[768 + j] + bhh1[768 + j];

  // weight row pointers, half-K windows
  const float4* whA0 = (const float4*)(Whh0 + (size_t)j * 256         + half * 128);
  const float4* whA1 = (const float4*)(Whh0 + (size_t)(256 + j) * 256 + half * 128);
  const float4* whA2 = (const float4*)(Whh0 + (size_t)(512 + j) * 256 + half * 128);
  const float4* whA3 = (const float4*)(Whh0 + (size_t)(768 + j) * 256 + half * 128);
  const float4* wiA0 = (const float4*)(Wih0 + (size_t)j * 128         + half * 64);
  const float4* wiA1 = (const float4*)(Wih0 + (size_t)(256 + j) * 128 + half * 64);
  const float4* wiA2 = (const float4*)(Wih0 + (size_t)(512 + j) * 128 + half * 64);
  const float4* wiA3 = (const float4*)(Wih0 + (size_t)(768 + j) * 128 + half * 64);
  const float4* wiB0 = (const float4*)(Wih1 + (size_t)j * 256         + half * 128);
  const float4* wiB1 = (const float4*)(Wih1 + (size_t)(256 + j) * 256 + half * 128);
  const float4* wiB2 = (const float4*)(Wih1 + (size_t)(512 + j) * 256 + half * 128);
  const float4* wiB3 = (const float4*)(Wih1 + (size_t)(768 + j) * 256 + half * 128);
  const float4* whB0 = (const float4*)(Whh1 + (size_t)j * 256         + half * 128);
  const float4* whB1 = (const float4*)(Whh1 + (size_t)(256 + j) * 256 + half * 128);
  const float4* whB2 = (const float4*)(Whh1 + (size_t)(512 + j) * 256 + half * 128);
  const float4* whB3 = (const float4*)(Whh1 + (size_t)(768 + j) * 256 + half * 128);

  float c0r = 0.f, c1r = 0.f;      // block-local cell state (half==0 threads)
  unsigned int tgt = 0;

  for (int p = 0; p <= T_LEN; p++) {
    const int cur = p & 1, prv = cur ^ 1;

    // ---- stage h0[p-1], h1[p-2] for our 4 batches (8 agent loads/thread) ----
    for (int i = tid; i < 1024; i += 256) {
      int bb = i >> 8, k = i & 255;
      float v0 = gload(h0buf + prv * 8192 + (size_t)(bg * 4 + bb) * 256 + k);
      float v1 = gload(h1buf + prv * 8192 + (size_t)(bg * 4 + bb) * 256 + k);
      h0p[bb * 264 + k] = v0;
      h1p[bb * 264 + k] = v1;
    }
    __syncthreads();

    // ---- layer 0, step t = p ----
    if (p < T_LEN) {
      float a0 = 0.f, a1 = 0.f, a2 = 0.f, a3 = 0.f;
      const float4* h4 = (const float4*)(h0p + bl * 264) + half * 32;
      #pragma unroll 8
      for (int k4 = 0; k4 < 32; k4++) {
        float4 hv = h4[k4];
        float4 w0 = whA0[k4], w1 = whA1[k4], w2 = whA2[k4], w3 = whA3[k4];
        a0 += hv.x * w0.x + hv.y * w0.y + hv.z * w0.z + hv.w * w0.w;
        a1 += hv.x * w1.x + hv.y * w1.y + hv.z * w1.z + hv.w * w1.w;
        a2 += hv.x * w2.x + hv.y * w2.y + hv.z * w2.z + hv.w * w2.w;
        a3 += hv.x * w3.x + hv.y * w3.y + hv.z * w3.z + hv.w * w3.w;
      }
      const float4* xp = (const float4*)(pooled + ((size_t)(b * 256 + p)) * 128 + half * 64);
      #pragma unroll 8
      for (int k4 = 0; k4 < 16; k4++) {
        float4 xv = xp[k4];
        float4 w0 = wiA0[k4], w1 = wiA1[k4], w2 = wiA2[k4], w3 = wiA3[k4];
        a0 += xv.x * w0.x + xv.y * w0.y + xv.z * w0.z + xv.w * w0.w;
        a1 += xv.x * w1.x + xv.y * w1.y + xv.z * w1.z + xv.w * w1.w;
        a2 += xv.x * w2.x + xv.y * w2.y + xv.z * w2.z + xv.w * w2.w;
        a3 += xv.x * w3.x + xv.y * w3.y + xv.z * w3.z + xv.w * w3.w;
      }
      a0 += __shfl_xor(a0, 1); a1 += __shfl_xor(a1, 1);
      a2 += __shfl_xor(a2, 1); a3 += __shfl_xor(a3, 1);
      if (half == 0) {
        float iv = sigmoidf_(a0 + bA0);
        float fv = sigmoidf_(a1 + bA1);
        float gv = tanhf(a2 + bA2);
        float ov = sigmoidf_(a3 + bA3);
        float cnew = fv * c0r + iv * gv;
        float hnew = ov * tanhf(cnew);
        bool valid = p < len_b;
        float hout = valid ? hnew : h0p[bl * 264 + j];
        if (valid) c0r = cnew;
        gstore(h0buf + cur * 8192 + (size_t)b * 256 + j, hout);
      }
    }

    // ---- layer 1, step s = p-1 (input = h0[p-1], recurrent = h1[p-2]) ----
    if (p >= 1) {
      float s0 = 0.f, s1 = 0.f, s2 = 0.f, s3 = 0.f;
      const float4* x4 = (const float4*)(h0p + bl * 264) + half * 32;
      const float4* h4 = (const float4*)(h1p + bl * 264) + half * 32;
      #pragma unroll 8
      for (int k4 = 0; k4 < 32; k4++) {
        float4 xv = x4[k4];
        float4 hv = h4[k4];
        float4 u0 = wiB0[k4], u1 = wiB1[k4], u2 = wiB2[k4], u3 = wiB3[k4];
        float4 w0 = whB0[k4], w1 = whB1[k4], w2 = whB2[k4], w3 = whB3[k4];
        s0 += xv.x * u0.x + xv.y * u0.y + xv.z * u0.z + xv.w * u0.w
            + hv.x * w0.x + hv.y * w0.y + hv.z * w0.z + hv.w * w0.w;
        s1 += xv.x * u1.x + xv.y * u1.y + xv.z * u1.z + xv.w * u1.w
            + hv.x * w1.x + hv.y * w1.y + hv.z * w1.z + hv.w * w1.w;
        s2 += xv.x * u2.x + xv.y * u2.y + xv.z * u2.z + xv.w * u2.w
            + hv.x * w2.x + hv.y * w2.y + hv.z * w2.z + hv.w * w2.w;
        s3 += xv.x * u3.x + xv.y * u3.y + xv.z * u3.z + xv.w * u3.w
            + hv.x * w3.x + hv.y * w3.y + hv.z * w3.z + hv.w * w3.w;
      }
      s0 += __shfl_xor(s0, 1); s1 += __shfl_xor(s1, 1);
      s2 += __shfl_xor(s2, 1); s3 += __shfl_xor(s3, 1);
      if (half == 0) {
        float iv = sigmoidf_(s0 + bB0);
        float fv = sigmoidf_(s1 + bB1);
        float gv = tanhf(s2 + bB2);
        float ov = sigmoidf_(s3 + bB3);
        float cnew = fv * c1r + iv * gv;
        float hnew = ov * tanhf(cnew);
        bool valid = (p - 1) < len_b;
        float hout = valid ? hnew : h1p[bl * 264 + j];
        if (valid) c1r = cnew;
        gstore(h1buf + cur * 8192 + (size_t)b * 256 + j, hout);
      }
    }

    tgt += NBLK_SEQ;
    gbar(cnt, tgt);
  }

  // classifier: h1[255] was published at p=256 into h1buf[0].
  if (blockIdx.x == 0 && tid < 32) {
    float s = clfb[0];
    const float* hl = h1buf + 0 * 8192 + (size_t)tid * 256;
    for (int k = 0; k < 256; k++) s += gload(hl + k) * clfw[k];
    out[tid] = s;
  }
}

// ---------------------------------------------------------------------------
extern "C" void kernel_launch(void* const* d_in, const int* in_sizes, int n_in,
                              void* d_out, int out_size, void* d_ws, size_t ws_size,
                              hipStream_t stream) {
  (void)in_sizes; (void)n_in; (void)out_size; (void)ws_size;
  const float* feat = (const float*)d_in[0];
  const int*   lens = (const int*)d_in[1];
  const float* W1   = (const float*)d_in[2];
  const float* as1  = (const float*)d_in[3];
  const float* ad1  = (const float*)d_in[4];
  const float* b1   = (const float*)d_in[5];
  const float* W2   = (const float*)d_in[6];
  const float* as2  = (const float*)d_in[7];
  const float* ad2  = (const float*)d_in[8];
  const float* b2   = (const float*)d_in[9];
  const float* Wih0 = (const float*)d_in[10];
  const float* Whh0 = (const float*)d_in[11];
  const float* bih0 = (const float*)d_in[12];
  const float* bhh0 = (const float*)d_in[13];
  const float* Wih1 = (const float*)d_in[14];
  const float* Whh1 = (const float*)d_in[15];
  const float* bih1 = (const float*)d_in[16];
  const float* bhh1 = (const float*)d_in[17];
  const float* clfw = (const float*)d_in[18];
  const float* clfb = (const float*)d_in[19];

  float* ws     = (float*)d_ws;
  float* pooled = ws + 65536;   // [8192][128] -> total ws use 4.25 MB
  float* outp   = (float*)d_out;

  // zero barrier counter + h0/h1 double buffers
  hipMemsetAsync(d_ws, 0, 65536 * sizeof(float), stream);

  gat_naive<<<8192, 256, 0, stream>>>(feat, lens, W1, as1, ad1, b1,
                                      W2, as2, ad2, b2, pooled);

  void* args[] = {
    (void*)&pooled, (void*)&Wih0, (void*)&bih0, (void*)&bhh0, (void*)&Whh0,
    (void*)&Wih1, (void*)&Whh1, (void*)&bih1, (void*)&bhh1,
    (void*)&lens, (void*)&clfw, (void*)&clfb, (void*)&ws, (void*)&outp
  };
  hipLaunchCooperativeKernel((const void*)lstm_pipe, dim3(NBLK_SEQ), dim3(256),
                             args, 0, stream);
}